// Round 5
// baseline (243.568 us; speedup 1.0000x reference)
//
#include <hip/hip_runtime.h>
#include <math.h>

// Problem constants (from setup_inputs)
#define T_TOTAL 2097152
#define A_DIM   18
#define GAMMA_D 0.99

// Scan blocking: chunk == block size
#define CHUNK 256
#define NC    (T_TOTAL / CHUNK)        // 8192 chunks == k_main blocks
#define KTR   14                       // G^14 ~ 2e-16, G = 0.99^256
#define G256  0.076314983205510425     // 0.99^256

// g^e by 8-bit exponent squaring: ~16 f64 mults, no libcall.
__device__ inline double pow_tid(double base, int e) {
    double p = 1.0, b = base;
    #pragma unroll
    for (int bit = 0; bit < 8; ++bit) {
        if (e & (1 << bit)) p *= b;
        b *= b;
    }
    return p;
}

// ---------------------------------------------------------------------------
// Kernel A (main): ONE chunk of 256 rows per block; carry-free.
// Emits per chunk: {L_c, sum dl, sum nlp, sum nlp*dl, sum nlp*g^-tid}
// where dl = chunk-local discounted return (carry applied later in k_final).
__launch_bounds__(256)
__global__ void k_main(const float* __restrict__ wgt, const int* __restrict__ act,
                       const float* __restrict__ r, double* __restrict__ partials) {
    __shared__ float  lds[CHUNK * A_DIM];     // 18 KiB
    __shared__ double ldsT[4];                // per-wave scan totals
    __shared__ double red[16];
    const int tid  = threadIdx.x;
    const int lane = tid & 63, wv = tid >> 6;
    const int c    = blockIdx.x;
    const double g  = GAMMA_D;
    const double p  = pow_tid(g, tid);         // g^tid
    const double ip = pow_tid(1.0 / g, tid);   // g^-tid (<= ~13.1)

    // ---- stage weight tile (coalesced float4) ----
    const float4* src = (const float4*)(wgt + (size_t)c * CHUNK * A_DIM);
    float4* dst = (float4*)lds;
    #pragma unroll
    for (int i = 0; i < 5; ++i) {
        int idx = tid + 256 * i;
        if (idx < CHUNK * A_DIM / 4) dst[idx] = src[idx];
    }
    // ---- wave suffix scan (scaled space), pre-barrier ----
    const int row = c * CHUNK + tid;
    double ss = p * (double)r[row];
    #pragma unroll
    for (int off = 1; off < 64; off <<= 1) {
        double v = __shfl_down(ss, off, 64);
        ss += (lane + off < 64) ? v : 0.0;
    }
    if (lane == 0) ldsT[wv] = ss;
    __syncthreads();                           // staging + ldsT both visible
    double tail = 0.0;
    #pragma unroll
    for (int m = 0; m < 4; ++m)
        if (m > wv) tail += ldsT[m];
    const double Lc = ss + tail;               // at tid==0 this is L_c
    const double dl = ip * Lc;                 // chunk-local d (no carry)

    // ---- f32 logsumexp (matches reference dtype) ----
    const float* wr = lds + tid * A_DIM;
    float mx = wr[0];
    #pragma unroll
    for (int j = 1; j < A_DIM; ++j) mx = fmaxf(mx, wr[j]);
    float s = 0.0f;
    #pragma unroll
    for (int j = 0; j < A_DIM; ++j) s += expf(wr[j] - mx);
    const float nlp = mx + logf(s) - wr[act[row]];

    double s_dl  = dl;
    double s_n   = (double)nlp;
    double s_ndl = (double)nlp * dl;
    double s_p   = (double)nlp * ip;

    // ---- block reduction (4 sums) ----
    #pragma unroll
    for (int off = 32; off > 0; off >>= 1) {
        s_dl  += __shfl_down(s_dl,  off, 64);
        s_n   += __shfl_down(s_n,   off, 64);
        s_ndl += __shfl_down(s_ndl, off, 64);
        s_p   += __shfl_down(s_p,   off, 64);
    }
    if (lane == 0) {
        red[wv*4+0] = s_dl; red[wv*4+1] = s_n;
        red[wv*4+2] = s_ndl; red[wv*4+3] = s_p;
    }
    __syncthreads();
    if (tid == 0) {
        double a = 0.0, b = 0.0, cc = 0.0, d = 0.0;
        #pragma unroll
        for (int i = 0; i < 4; ++i) {
            a += red[i*4+0]; b += red[i*4+1]; cc += red[i*4+2]; d += red[i*4+3];
        }
        double* out5 = partials + (size_t)c * 5;
        out5[0] = Lc;    // tid0's ss+tail == full chunk-local sum
        out5[1] = a;     // sum dl
        out5[2] = b;     // sum nlp
        out5[3] = cc;    // sum nlp*dl
        out5[4] = d;     // sum nlp*g^-tid
    }
}

// ---------------------------------------------------------------------------
// Kernel B (final): per-thread sliding window of 32 consecutive chunks with
// the EXACT carry recurrence carry[c] = L[c+1] + G*carry[c+1] (seed truncated
// at 14 terms, G^14 ~ 2e-16); combine with per-chunk partials; write scalar.
__global__ void k_final(const double* __restrict__ partials, float* __restrict__ out) {
    __shared__ double red[12];
    const int tid = threadIdx.x;               // 256 threads
    const double g = GAMMA_D, G = G256;
    const int lo = tid * (NC / 256), hi = lo + (NC / 256) - 1;

    // seed: carry[hi] = sum_{m=0..13} G^m L[hi+1+m]  (bounds-guarded)
    double carry = 0.0, w = 1.0;
    #pragma unroll
    for (int m = 0; m < KTR; ++m) {
        int idx = hi + 1 + m;
        if (idx < NC) carry += w * partials[(size_t)idx * 5 + 0];
        w *= G;
    }
    const double K0 = (1.0 / G - 1.0) / (1.0 / g - 1.0);  // sum g^-tid, tid<256

    double a = 0.0, b = 0.0, cc = 0.0;
    for (int c = hi; c >= lo; --c) {
        if (c != hi) carry = partials[(size_t)(c + 1) * 5 + 0] + G * carry;
        const double* p5 = partials + (size_t)c * 5;
        const double gc = G * carry;
        a  += p5[1] + gc * K0;      // sum d
        b  += p5[2];                // sum nlp
        cc += p5[3] + gc * p5[4];   // sum nlp*d
    }

    #pragma unroll
    for (int off = 32; off > 0; off >>= 1) {
        a  += __shfl_down(a,  off, 64);
        b  += __shfl_down(b,  off, 64);
        cc += __shfl_down(cc, off, 64);
    }
    const int lane = tid & 63, wv = tid >> 6;
    if (lane == 0) { red[wv*3+0] = a; red[wv*3+1] = b; red[wv*3+2] = cc; }
    __syncthreads();
    if (tid == 0) {
        double A_ = 0.0, B_ = 0.0, C_ = 0.0;
        #pragma unroll
        for (int i = 0; i < 4; ++i) { A_ += red[i*3]; B_ += red[i*3+1]; C_ += red[i*3+2]; }
        const double invT = 1.0 / (double)T_TOTAL;
        // out = (1/T) * ( sum(nlp*d) - mean(d) * sum(nlp) )
        out[0] = (float)((C_ - (A_ * invT) * B_) * invT);
    }
}

// ---------------------------------------------------------------------------
extern "C" void kernel_launch(void* const* d_in, const int* in_sizes, int n_in,
                              void* d_out, int out_size, void* d_ws, size_t ws_size,
                              hipStream_t stream) {
    const float* weight = (const float*)d_in[0];   // [T, 18] f32
    const float* ep_rs  = (const float*)d_in[1];   // [T] f32
    const int*   ep_as  = (const int*)  d_in[2];   // [T] int
    float* out = (float*)d_out;

    double* partials = (double*)d_ws;              // NC*5 doubles (320 KiB)

    k_main  <<<NC, 256, 0, stream>>>(weight, ep_as, ep_rs, partials);
    k_final <<<1,  256, 0, stream>>>(partials, out);
}